// Round 15
// baseline (113.773 us; speedup 1.0000x reference)
//
#include <hip/hip_runtime.h>
#include <math.h>

#define H 256
#define W 256
#define HW (H * W)
#define CH 24
#define NK 63
#define KSTEPS 25       // K = 25 taps * 32 (24 ch + 8 zero-pad in A-frags)
#define NE 257          // table dwords per channel (pairs of 258 samples)
#define TBLN (CH * NE)  // 6168 dwords per table
#define PXS 32          // per-pixel stride in shorts (64 B) -> linear lane map
#define T3S 26          // t3 per-pixel stride in floats

typedef short v8s __attribute__((ext_vector_type(8)));
typedef short v4s __attribute__((ext_vector_type(4)));
typedef float v4f __attribute__((ext_vector_type(4)));

// ---------------- bf16 helper ----------------------------------------------------
__device__ __forceinline__ short f2bf(float v) {
    unsigned u = __float_as_uint(v);
    u += 0x7fff + ((u >> 16) & 1);
    return (short)(u >> 16);
}

// ---------------- table lookup (global, L1-resident) ------------------------------
struct TblCtx { float off, invh; };
__device__ __forceinline__ TblCtx make_tctx(const float* __restrict__ mean) {
    TblCtx c;
    float lo = mean[0] - 12.f;
    float hi = mean[NK - 1] + 12.f;
    c.invh = 257.f / (hi - lo);
    c.off  = -lo * c.invh;
    return c;
}
__device__ __forceinline__ float tbl_eval(const unsigned* __restrict__ tbl, int ch,
                                          float v, const TblCtx& c) {
    float t = fmaf(v, c.invh, c.off);
    t = fminf(fmaxf(t, 0.f), 256.999f);
    float fi = floorf(t);
    float fr = t - fi;
    unsigned u = tbl[ch * NE + (int)fi];        // global dword, L1-hit
    float a = __uint_as_float(u << 16);
    float b = __uint_as_float(u & 0xffff0000u);
    return fmaf(fr, b - a, a);
}

// ---------------- LDS union: 41 KB -> 3 blocks/CU ----------------------------------
struct Smem {
    union {
        short t1[400 * PXS];      // 20x20 rbf0(conv1) tile (25600 B), ph1->ph2
        float t3[144 * T3S];      // 12x12 rbf_der tile (14976 B),    ph3->ph4
    } u1;
    union {
        float xs[576];            // 24x24 x window (2304 B), ph1
        short tbt[256 * PXS];     // 16x16 rbf1(conv2) tile (16384 B), ph2->ph3
        float red[256];           // reduction buf, ph4
    } u2;
};

// ---------------- prep: norms, f0n/f0t, A-frag pack, RBF tables --------------------
// abuf: [mode 2][mtile 2][kstep 25][lane 64] v8s. k = tap*32 + c (c<24, pad=0).
// tables: tg[tt][ch][NE], tt: 0=rbf(aw0), 1=rbf(aw1), 2=rbf_der(aw0); exact 63-tap.
__global__ void k_prep(const float* __restrict__ f0, const float* __restrict__ f1,
                       const float* __restrict__ mean, const float* __restrict__ aw0,
                       const float* __restrict__ aw1,
                       float* __restrict__ f0n, float* __restrict__ f0t,
                       v8s* __restrict__ abuf, unsigned* __restrict__ tg) {
    __shared__ float red[256];
    int tid = threadIdx.x;
    float s1 = 0.f;
    for (int i = tid; i < 14400; i += 256) s1 += f1[i] * f1[i];
    red[tid] = s1; __syncthreads();
    for (int off = 128; off; off >>= 1) { if (tid < off) red[tid] += red[tid + off]; __syncthreads(); }
    float inv1 = 1.f / sqrtf(red[0]);
    __syncthreads();
    if (blockIdx.x == 0) {
        float s0 = 0.f;
        for (int i = tid; i < 600; i += 256) s0 += f0[i] * f0[i];
        red[tid] = s0; __syncthreads();
        for (int off = 128; off; off >>= 1) { if (tid < off) red[tid] += red[tid + off]; __syncthreads(); }
        float inv0 = 1.f / sqrtf(red[0]);
        for (int i = tid; i < 600; i += 256) {
            int c = i / 25, k = i % 25;
            f0n[i] = f0[i] * inv0;
            f0t[i] = f0[c * 25 + (24 - k)] * inv0;
        }
    }
    int gid = blockIdx.x * 256 + tid;      // 75 blocks -> 19200 threads
    if (gid < 6400) {                      // A-fragment pack
        int lane = gid & 63;
        int rest = gid >> 6;               // 0..99
        int s = rest % KSTEPS;
        int md = rest / KSTEPS;            // 0..3
        int mode = md >> 1, m = md & 1;
        int o = m * 16 + (lane & 15);
        v8s av;
        #pragma unroll
        for (int j = 0; j < 8; ++j) {
            int c = 8 * (lane >> 4) + j;
            float wv = 0.f;
            if (o < CH && c < CH) {
                wv = (mode == 0) ? f1[(o * CH + c) * 25 + s]
                                 : f1[(c * CH + o) * 25 + (24 - s)];
                wv *= inv1;
            }
            av[j] = f2bf(wv);
        }
        abuf[gid] = av;
    }
    // RBF tables: 18504 jobs, one per thread
    float lo = mean[0] - 12.f;
    float hi = mean[NK - 1] + 12.f;
    float h  = (hi - lo) * (1.f / 257.f);
    if (gid < 3 * TBLN) {
        int tt = gid / TBLN;
        int rest = gid - tt * TBLN;
        int ch = rest / NE;
        int i  = rest - ch * NE;
        const float* wr = ((tt == 1) ? aw1 : aw0) + ch * NK;
        float v0 = fmaf(h, (float)i, lo);
        float v1 = v0 + h;
        float s0 = 0.f, s1v = 0.f;
        for (int k = 0; k < NK; ++k) {
            float m = mean[k], wk = wr[k];
            float d0 = v0 - m, d1 = v1 - m;
            float e0 = __expf(d0 * d0 * -0.005f);
            float e1 = __expf(d1 * d1 * -0.005f);
            if (tt == 2) { e0 *= d0 * -0.01f; e1 *= d1 * -0.01f; }
            s0 = fmaf(e0, wk, s0);
            s1v = fmaf(e1, wk, s1v);
        }
        unsigned pb = ((unsigned)(unsigned short)f2bf(s1v) << 16)
                    | (unsigned)(unsigned short)f2bf(s0);
        tg[gid] = pb;
    }
}

// ---------------- fused main: all 4 stages, intermediates in LDS -------------------
// 8x8 output tile, 1024 blocks, 3 blocks/CU (41 KB LDS, VGPR cap ~170: no spill).
__global__ __launch_bounds__(256, 3) void k_main(
        const float* __restrict__ x, const float* __restrict__ y,
        const float* __restrict__ f0n, const float* __restrict__ f0t,
        const v8s* __restrict__ abuf, const float* __restrict__ mean,
        const unsigned* __restrict__ T0g, const unsigned* __restrict__ T1g,
        const unsigned* __restrict__ TDg, const float* __restrict__ lamp,
        float* __restrict__ out) {
    __shared__ Smem sm;
    int tid = threadIdx.x;
    int x0 = (blockIdx.x & 31) * 8, y0 = (blockIdx.x >> 5) * 8;
    TblCtx ctx = make_tctx(mean);
    const v8s zv = {0,0,0,0,0,0,0,0};

    // stage: x window 24x24 at origin (y0-8, x0-8), clamped (= replication pad);
    // also zero the ch-24..31 pad of every t1 pixel (q=3 B-reads must be finite).
    for (int i = tid; i < 576; i += 256) {
        int r = i / 24, cL = i % 24;
        int gy = min(max(y0 + r - 8, 0), H - 1);
        int gx = min(max(x0 + cL - 8, 0), W - 1);
        sm.u2.xs[i] = x[gy * W + gx];
    }
    for (int i = tid; i < 400; i += 256)
        *(v8s*)&sm.u1.t1[i * PXS + 24] = zv;
    __syncthreads();

    // ---- phase 1: t1 = rbf0(conv1(x)) on 20x20 (origin y0-6, x0-6) ----
    // 1200 jobs = (og 0..2) x (px 0..399)
    #pragma unroll 1
    for (int j = tid; j < 1200; j += 256) {
        int og = j / 400;
        int px = j - og * 400;
        int yi = px / 20;
        int xi = px - yi * 20;
        int sy = min(max(y0 + yi - 6, 0), H - 1);
        int sx = min(max(x0 + xi - 6, 0), W - 1);
        int iy[5], ix[5];
        #pragma unroll
        for (int u = 0; u < 5; ++u) {
            iy[u] = min(max(sy + u - 2, 0), H - 1) - (y0 - 8);
            ix[u] = min(max(sx + u - 2, 0), W - 1) - (x0 - 8);
        }
        float in_[25];
        #pragma unroll
        for (int u = 0; u < 5; ++u)
            #pragma unroll
            for (int v = 0; v < 5; ++v) in_[u * 5 + v] = sm.u2.xs[iy[u] * 24 + ix[v]];
        v8s pk;
        #pragma unroll
        for (int oj = 0; oj < 8; ++oj) {
            int o = og * 8 + oj;
            float a = 0.f;
            #pragma unroll
            for (int k = 0; k < 25; ++k) a = fmaf(in_[k], f0n[o * 25 + k], a);
            pk[oj] = f2bf(tbl_eval(T0g, o, a, ctx));
        }
        *(v8s*)&sm.u1.t1[px * PXS + og * 8] = pk;
    }
    __syncthreads();

    // ---- phase 2: tbt = rbf1(conv2(t1)) on 16x16 (origin y0-4, x0-4), LDS only ----
    int lane = tid & 63, wv_ = tid >> 6;
    int p = lane & 15, q = lane >> 4;
    {
        v4f a0[4], a1[4];
        #pragma unroll
        for (int g = 0; g < 4; ++g) { a0[g] = (v4f){0.f,0.f,0.f,0.f}; a1[g] = (v4f){0.f,0.f,0.f,0.f}; }
        #pragma unroll
        for (int s = 0; s < KSTEPS; ++s) {
            const int u = s / 5, v = s % 5;            // compile-time
            v8s af0 = abuf[s * 64 + lane];
            v8s af1 = abuf[1600 + s * 64 + lane];
            #pragma unroll
            for (int g = 0; g < 4; ++g) {
                int row = wv_ * 4 + g;                 // wave owns 4 rows of 16
                v8s b = *(const v8s*)&sm.u1.t1[((row + u) * 20 + (p + v)) * PXS + q * 8];
                a0[g] = __builtin_amdgcn_mfma_f32_16x16x32_bf16(af0, b, a0[g], 0, 0, 0);
                a1[g] = __builtin_amdgcn_mfma_f32_16x16x32_bf16(af1, b, a1[g], 0, 0, 0);
            }
        }
        __syncthreads();   // all t1 reads complete (t3 will overlay t1 in ph3);
                           // tbt overlays xs (dead since ph1) -> safe to write.
        #pragma unroll
        for (int g = 0; g < 4; ++g) {
            int row = wv_ * 4 + g;
            int gy = y0 - 4 + row, gx = x0 - 4 + p;
            bool inimg = (gy >= 0 && gy < H && gx >= 0 && gx < W);
            v4s st;
            #pragma unroll
            for (int j = 0; j < 4; ++j)
                st[j] = inimg ? f2bf(tbl_eval(T1g, q * 4 + j, a0[g][j], ctx)) : (short)0;
            *(v4s*)&sm.u2.tbt[(row * 16 + p) * PXS + q * 4] = st;
            if (q < 2) {
                #pragma unroll
                for (int j = 0; j < 4; ++j)
                    st[j] = inimg ? f2bf(tbl_eval(T1g, 16 + q * 4 + j, a1[g][j], ctx)) : (short)0;
                *(v4s*)&sm.u2.tbt[(row * 16 + p) * PXS + 16 + q * 4] = st;
            } else if (q == 3) {
                *(v8s*)&sm.u2.tbt[(row * 16 + p) * PXS + 24] = zv;   // ch pad
            }
        }
    }
    __syncthreads();

    // ---- phase 3: t3 = rbf'(convT2(tbt)) on 12x12 (origin y0-2, x0-2) ----
    // waves 0..2 own 3 N-tiles each (9 x 16 = 144 px); t3 overlays t1 (dead).
    if (wv_ < 3) {
        const v8s* ap = abuf + 3200;       // mode-1 fragments
        int base[3], frow[3], fcol[3];
        #pragma unroll
        for (int g = 0; g < 3; ++g) {
            int f = (wv_ * 3 + g) * 16 + p;
            int r_ = f / 12;
            frow[g] = r_; fcol[g] = f - r_ * 12;
            base[g] = (r_ * 16 + fcol[g]) * PXS + q * 8;
        }
        v4f c0[3], c1[3];
        #pragma unroll
        for (int g = 0; g < 3; ++g) { c0[g] = (v4f){0.f,0.f,0.f,0.f}; c1[g] = (v4f){0.f,0.f,0.f,0.f}; }
        #pragma unroll
        for (int s = 0; s < KSTEPS; ++s) {
            const int off = ((s / 5) * 16 + (s % 5)) * PXS;
            v8s af0 = ap[s * 64 + lane];
            v8s af1 = ap[1600 + s * 64 + lane];
            #pragma unroll
            for (int g = 0; g < 3; ++g) {
                v8s b = *(const v8s*)&sm.u2.tbt[base[g] + off];
                c0[g] = __builtin_amdgcn_mfma_f32_16x16x32_bf16(af0, b, c0[g], 0, 0, 0);
                c1[g] = __builtin_amdgcn_mfma_f32_16x16x32_bf16(af1, b, c1[g], 0, 0, 0);
            }
        }
        #pragma unroll
        for (int g = 0; g < 3; ++g) {
            int f = (wv_ * 3 + g) * 16 + p;
            int gy = y0 + frow[g] - 2, gx = x0 + fcol[g] - 2;
            bool inimg = (gy >= 0 && gy < H && gx >= 0 && gx < W);
            #pragma unroll
            for (int j = 0; j < 4; ++j)
                sm.u1.t3[f * T3S + q * 4 + j] =
                    inimg ? tbl_eval(TDg, q * 4 + j, c0[g][j], ctx) : 0.f;
            if (q < 2) {
                #pragma unroll
                for (int j = 0; j < 4; ++j)
                    sm.u1.t3[f * T3S + 16 + q * 4 + j] =
                        inimg ? tbl_eval(TDg, 16 + q * 4 + j, c1[g][j], ctx) : 0.f;
            }
        }
    }
    __syncthreads();

    // ---- phase 4: convT1 (24->1, pre-flipped f0t) + final combine ----
    int gq = __builtin_amdgcn_readfirstlane(tid >> 6);
    int px4 = tid & 63, pr = px4 >> 3, pc = px4 & 7;
    float a = 0.f;
    #pragma unroll 1
    for (int cp = 0; cp < 3; ++cp) {
        int c = gq * 6 + cp * 2;               // even -> 8B-aligned float2
        const float* fb0 = f0t + c * 25;
        const float* fb1 = f0t + (c + 1) * 25;
        #pragma unroll
        for (int u = 0; u < 5; ++u)
            #pragma unroll
            for (int v = 0; v < 5; ++v) {
                float2 tp = *(const float2*)&sm.u1.t3[((pr + u) * 12 + (pc + v)) * T3S + c];
                a = fmaf(tp.x, fb0[u * 5 + v], a);
                a = fmaf(tp.y, fb1[u * 5 + v], a);
            }
    }
    sm.u2.red[tid] = a;       // red overlays tbt (u2): t3 is u1, no clash
    __syncthreads();
    if (tid < 64) {
        float tot = sm.u2.red[tid] + sm.u2.red[64 + tid]
                  + sm.u2.red[128 + tid] + sm.u2.red[192 + tid];
        int pix = (y0 + pr) * W + (x0 + pc);
        float elam = __expf(lamp[0]);
        float xv = x[pix], yv = y[pix];
        out[pix] = xv - (tot + elam * (xv - yv));
    }
}

extern "C" void kernel_launch(void* const* d_in, const int* in_sizes, int n_in,
                              void* d_out, int out_size, void* d_ws, size_t ws_size,
                              hipStream_t stream) {
    const float* x    = (const float*)d_in[0];
    const float* y    = (const float*)d_in[1];
    const float* f0   = (const float*)d_in[3];
    const float* f1   = (const float*)d_in[4];
    const float* aw0  = (const float*)d_in[5];
    const float* aw1  = (const float*)d_in[6];
    const float* mean = (const float*)d_in[7];
    const float* lamp = (const float*)d_in[8];
    float* out = (float*)d_out;

    float* w   = (float*)d_ws;
    float* f0n = w;                          // 600
    float* f0t = w + 640;                    // 600
    v8s*  abuf = (v8s*)(w + 1536);           // 6400*16B -> ends at w+27136
    unsigned* tg = (unsigned*)(w + 27136);   // 3*6168 dwords
    unsigned* T0g = tg;
    unsigned* T1g = tg + TBLN;
    unsigned* TDg = tg + 2 * TBLN;

    k_prep<<<75, 256, 0, stream>>>(f0, f1, mean, aw0, aw1, f0n, f0t, abuf, tg);
    k_main<<<1024, 256, 0, stream>>>(x, y, f0n, f0t, abuf, mean, T0g, T1g, TDg, lamp, out);
}

// Round 16
// 58.467 us; speedup vs baseline: 1.9459x; 1.9459x over previous
//
#include <hip/hip_runtime.h>
#include <math.h>

#define H 256
#define W 256
#define HW (H * W)
#define CH 24
#define NK 63
#define PXS 40          // t1 per-pixel stride in shorts (80 B = 20 dwords, 2-way floor)
#define TBS 24          // tbt per-pixel stride in shorts (48 B = 12 dwords, 2-way floor)
#define KSTEPS 25       // K = 25 taps * 32 (24 ch + 8 zero-pad)
#define T3S 26          // t3 per-pixel stride in floats

typedef short v8s __attribute__((ext_vector_type(8)));
typedef short v4s __attribute__((ext_vector_type(4)));
typedef float v4f __attribute__((ext_vector_type(4)));

// ---------------- analytic RBF ------------------------------------------------
struct RbfCtx {
    float m0, istep, c2a, ahalf, dfac;
    float G1, G2, G3, G4;
};
__device__ __forceinline__ RbfCtx make_ctx(const float* __restrict__ mean) {
    RbfCtx c;
    c.m0 = mean[0];
    float m62 = mean[NK - 1];
    float step = (m62 - c.m0) * (1.f / (float)(NK - 1));
    c.istep = (float)(NK - 1) / (m62 - c.m0);
    float a = step * step * (1.f / 200.f);
    c.c2a = 2.f * a;
    c.ahalf = a;
    c.dfac = -step * 0.01f;
    c.G1 = __expf(-a);
    c.G2 = __expf(-4.f * a);
    c.G3 = __expf(-9.f * a);
    c.G4 = __expf(-16.f * a);
    return c;
}

template<bool DER>
__device__ __forceinline__ float rbf_eval(float v, const float* __restrict__ wrow,
                                          const RbfCtx& c) {
    float t = (v - c.m0) * c.istep;
    float kcf = floorf(t + 0.5f);
    kcf = fminf(fmaxf(kcf, 4.f), (float)(NK - 5));
    int kc = (int)kcf;
    float f = t - kcf;
    f = fminf(fmaxf(f, -12.f), 12.f);
    float g  = c.c2a * f;
    float E1 = __expf(g), R1 = __expf(-g);
    float E2 = E1 * E1, R2 = R1 * R1;
    float gpm4 = c.G4 * R2 * R2, gpm3 = c.G3 * R2 * R1, gpm2 = c.G2 * R2, gpm1 = c.G1 * R1;
    float gpp1 = c.G1 * E1, gpp2 = c.G2 * E2, gpp3 = c.G3 * E2 * E1, gpp4 = c.G4 * E2 * E2;
    const float* p = wrow + (kc - 4);
    float m_m4 = p[0] * gpm4, m_m3 = p[1] * gpm3, m_m2 = p[2] * gpm2, m_m1 = p[3] * gpm1;
    float m_0  = p[4];
    float m_p1 = p[5] * gpp1, m_p2 = p[6] * gpp2, m_p3 = p[7] * gpp3, m_p4 = p[8] * gpp4;
    float S0 = ((m_m4 + m_m3) + (m_m2 + m_m1)) + m_0 + ((m_p1 + m_p2) + (m_p3 + m_p4));
    float base = __expf(-c.ahalf * f * f);
    if (!DER) return base * S0;
    float S1 = 0.f;
    S1 = fmaf(m_m4, -4.f, S1); S1 = fmaf(m_m3, -3.f, S1);
    S1 = fmaf(m_m2, -2.f, S1); S1 = fmaf(m_m1, -1.f, S1);
    S1 = fmaf(m_p1,  1.f, S1); S1 = fmaf(m_p2,  2.f, S1);
    S1 = fmaf(m_p3,  3.f, S1); S1 = fmaf(m_p4,  4.f, S1);
    return c.dfac * base * fmaf(f, S0, -S1);
}

__device__ __forceinline__ short f2bf(float v) {
    unsigned u = __float_as_uint(v);
    u += 0x7fff + ((u >> 16) & 1);
    return (short)(u >> 16);
}

// ---------------- prep: norms + A-fragment pack --------------------------------
// abuf: [mode 2][mtile 2][kstep 25][lane 64] v8s. k = tap*32 + c (c<24, pad=0).
__global__ void k_prep(const float* __restrict__ f0, const float* __restrict__ f1,
                       float* __restrict__ f0n, float* __restrict__ f0t,
                       v8s* __restrict__ abuf) {
    __shared__ float red[256];
    int tid = threadIdx.x;
    float s1 = 0.f;
    for (int i = tid; i < 14400; i += 256) s1 += f1[i] * f1[i];
    red[tid] = s1; __syncthreads();
    for (int off = 128; off; off >>= 1) { if (tid < off) red[tid] += red[tid + off]; __syncthreads(); }
    float inv1 = 1.f / sqrtf(red[0]);
    __syncthreads();
    if (blockIdx.x == 0) {
        float s0 = 0.f;
        for (int i = tid; i < 600; i += 256) s0 += f0[i] * f0[i];
        red[tid] = s0; __syncthreads();
        for (int off = 128; off; off >>= 1) { if (tid < off) red[tid] += red[tid + off]; __syncthreads(); }
        float inv0 = 1.f / sqrtf(red[0]);
        for (int i = tid; i < 600; i += 256) {
            int c = i / 25, k = i % 25;
            f0n[i] = f0[i] * inv0;
            f0t[i] = f0[c * 25 + (24 - k)] * inv0;
        }
    }
    int gid = blockIdx.x * 256 + tid;      // 6400 jobs
    int lane = gid & 63;
    int rest = gid >> 6;                   // 0..99
    int s = rest % KSTEPS;
    int md = rest / KSTEPS;                // 0..3
    int mode = md >> 1, m = md & 1;
    int o = m * 16 + (lane & 15);
    v8s av;
    #pragma unroll
    for (int j = 0; j < 8; ++j) {
        int c = 8 * (lane >> 4) + j;
        float wv = 0.f;
        if (o < CH && c < CH) {
            wv = (mode == 0) ? f1[(o * CH + c) * 25 + s]
                             : f1[(c * CH + o) * 25 + (24 - s)];
            wv *= inv1;
        }
        av[j] = f2bf(wv);
    }
    abuf[gid] = av;
}

// ---------------- fused A: conv1+rbf0 -> conv2 MFMA + rbf1 ---------------------
// 8x8 output tile, 1024 blocks, 4 blocks/CU. t1 stride 40 (2-way floor).
__global__ __launch_bounds__(256, 4) void k_fuseA(const float* __restrict__ x,
        const float* __restrict__ f0n, const v8s* __restrict__ abuf,
        const float* __restrict__ mean, const float* __restrict__ aw0,
        const float* __restrict__ aw1, short* __restrict__ tb) {
    __shared__ float ws0[CH * NK];
    __shared__ float ws1[CH * NK];
    __shared__ float xs[256];
    __shared__ __align__(16) short t1[144 * PXS];
    int tid = threadIdx.x;
    int x0 = blockIdx.x * 8, y0 = blockIdx.y * 8;
    {   // stage x window (16x16, clamped = replication pad)
        int r = tid >> 4, cL = tid & 15;
        int gy = min(max(y0 + r - 4, 0), H - 1);
        int gx = min(max(x0 + cL - 4, 0), W - 1);
        xs[tid] = x[gy * W + gx];
    }
    for (int i = tid; i < CH * NK; i += 256) { ws0[i] = aw0[i]; ws1[i] = aw1[i]; }
    RbfCtx ctx = make_ctx(mean);
    __syncthreads();

    // stage 1: t1 = rbf0(conv1) on 12x12 haloed region
    if (tid < 144) {
        int yi = (tid * 5462) >> 16;        // tid / 12
        int xi = tid - yi * 12;
        int sy = min(max(y0 + yi - 2, 0), H - 1);
        int sx = min(max(x0 + xi - 2, 0), W - 1);
        int iy[5], ix[5];
        #pragma unroll
        for (int u = 0; u < 5; ++u) {
            iy[u] = min(max(sy + u - 2, 0), H - 1) - (y0 - 4);
            ix[u] = min(max(sx + u - 2, 0), W - 1) - (x0 - 4);
        }
        float in_[25];
        #pragma unroll
        for (int u = 0; u < 5; ++u)
            #pragma unroll
            for (int v = 0; v < 5; ++v) in_[u * 5 + v] = xs[iy[u] * 16 + ix[v]];
        #pragma unroll 1
        for (int og = 0; og < 3; ++og) {
            v8s pk;
            #pragma unroll
            for (int oj = 0; oj < 8; ++oj) {
                int o = og * 8 + oj;
                float a = 0.f;
                #pragma unroll
                for (int k = 0; k < 25; ++k) a = fmaf(in_[k], f0n[o * 25 + k], a);
                pk[oj] = f2bf(rbf_eval<false>(a, ws0 + o * NK, ctx));
            }
            *(v8s*)&t1[tid * PXS + og * 8] = pk;
        }
        v8s z = {0,0,0,0,0,0,0,0};
        *(v8s*)&t1[tid * PXS + 24] = z;     // ch 24..31 pad (q=3 reads)
    }
    __syncthreads();

    // stage 2: conv2 MFMA; wave = one 16-px N-tile (2 rows of 8)
    int lane = tid & 63, wv_ = tid >> 6;
    int p = lane & 15, q = lane >> 4;
    int row = (wv_ * 16 + p) >> 3, col = p & 7;
    const short* bbase = &t1[(row * 12 + col) * PXS + q * 8];
    v4f a0v = {0.f,0.f,0.f,0.f}, a1v = {0.f,0.f,0.f,0.f};
    #pragma unroll
    for (int s = 0; s < KSTEPS; ++s) {
        const int u = s / 5, v = s % 5;     // compile-time under full unroll
        v8s b   = *(const v8s*)&bbase[(u * 12 + v) * PXS];
        v8s af0 = abuf[s * 64 + lane];
        v8s af1 = abuf[1600 + s * 64 + lane];
        a0v = __builtin_amdgcn_mfma_f32_16x16x32_bf16(af0, b, a0v, 0, 0, 0);
        a1v = __builtin_amdgcn_mfma_f32_16x16x32_bf16(af1, b, a1v, 0, 0, 0);
    }
    // epilogue: rbf1 -> tb[pix][ch] (channel-minor), 8B stores
    int pix = (y0 + row) * W + (x0 + col);
    v4s st;
    #pragma unroll
    for (int j = 0; j < 4; ++j)
        st[j] = f2bf(rbf_eval<false>(a0v[j], ws1 + (q * 4 + j) * NK, ctx));
    *(v4s*)&tb[pix * 24 + q * 4] = st;
    if (q < 2) {
        #pragma unroll
        for (int j = 0; j < 4; ++j)
            st[j] = f2bf(rbf_eval<false>(a1v[j], ws1 + (16 + q * 4 + j) * NK, ctx));
        *(v4s*)&tb[pix * 24 + 16 + q * 4] = st;
    }
}

// ---------------- fused B: convT2 MFMA + rbf' -> convT1 + final ----------------
// 8x8 output tile, 1024 blocks, 4 blocks/CU (33 KB LDS).
// tbt stride 24 (2-way floor); tiles distributed (3,2,2,2) across waves.
__global__ __launch_bounds__(256, 4) void k_fuseB(const short* __restrict__ tb,
        const v8s* __restrict__ abuf, const float* __restrict__ f0t,
        const float* __restrict__ mean, const float* __restrict__ aw0,
        const float* __restrict__ x, const float* __restrict__ y,
        const float* __restrict__ lamp, float* __restrict__ out) {
    __shared__ float ws0[CH * NK];
    __shared__ __align__(16) short tbt[256 * TBS + 8];  // reused as red[] in ph4
    __shared__ float t3[144 * T3S];
    int tid = threadIdx.x;
    int x0 = blockIdx.x * 8, y0 = blockIdx.y * 8;
    {   // stage tb window: 16x16 px, zero pad outside image
        int r = tid >> 4, cL = tid & 15;
        int gy = y0 + r - 4, gx = x0 + cL - 4;
        v8s z = {0,0,0,0,0,0,0,0};
        if (gy >= 0 && gy < H && gx >= 0 && gx < W) {
            const v8s* src = (const v8s*)&tb[(gy * W + gx) * 24];
            *(v8s*)&tbt[tid * TBS]      = src[0];
            *(v8s*)&tbt[tid * TBS + 8]  = src[1];
            *(v8s*)&tbt[tid * TBS + 16] = src[2];
        } else {
            *(v8s*)&tbt[tid * TBS]      = z;
            *(v8s*)&tbt[tid * TBS + 8]  = z;
            *(v8s*)&tbt[tid * TBS + 16] = z;
        }
        if (tid == 0) *(v8s*)&tbt[256 * TBS] = z;   // tail pad (q=3, last px)
    }
    for (int i = tid; i < CH * NK; i += 256) ws0[i] = aw0[i];
    RbfCtx ctx = make_ctx(mean);
    __syncthreads();

    // convT2 MFMA (mode-1 A-frags): wave w owns tiles {w, w+4, w+8} -> (3,2,2,2)
    int lane = tid & 63, wv_ = tid >> 6;
    int p = lane & 15, q = lane >> 4;
    const v8s* ap = abuf + 3200;
    int base[3], frow[3], fcol[3];
    bool valid[3];
    #pragma unroll
    for (int g = 0; g < 3; ++g) {
        int tIdx = wv_ + 4 * g;
        valid[g] = (tIdx <= 8);
        int tc = valid[g] ? tIdx : 8;
        int f = tc * 16 + p;                 // flat t3 px < 144
        int r_ = (f * 5462) >> 16;           // f / 12
        frow[g] = r_; fcol[g] = f - r_ * 12;
        base[g] = (r_ * 16 + fcol[g]) * TBS + q * 8;
    }
    v4f acc0[3], acc1[3];
    #pragma unroll
    for (int g = 0; g < 3; ++g) { acc0[g] = (v4f){0.f,0.f,0.f,0.f}; acc1[g] = (v4f){0.f,0.f,0.f,0.f}; }
    #pragma unroll
    for (int s = 0; s < KSTEPS; ++s) {
        const int off = ((s / 5) * 16 + (s % 5)) * TBS;   // compile-time
        v8s af0 = ap[s * 64 + lane];
        v8s af1 = ap[1600 + s * 64 + lane];
        #pragma unroll
        for (int g = 0; g < 3; ++g) {
            v8s b = *(const v8s*)&tbt[base[g] + off];
            acc0[g] = __builtin_amdgcn_mfma_f32_16x16x32_bf16(af0, b, acc0[g], 0, 0, 0);
            acc1[g] = __builtin_amdgcn_mfma_f32_16x16x32_bf16(af1, b, acc1[g], 0, 0, 0);
        }
    }
    // rbf_der -> t3 (zero outside image)
    #pragma unroll
    for (int g = 0; g < 3; ++g) {
        if (valid[g]) {
            int f = (wv_ + 4 * g) * 16 + p;
            int gy = y0 + frow[g] - 2, gx = x0 + fcol[g] - 2;
            bool inimg = (gy >= 0 && gy < H && gx >= 0 && gx < W);
            #pragma unroll
            for (int j = 0; j < 4; ++j)
                t3[f * T3S + q * 4 + j] =
                    inimg ? rbf_eval<true>(acc0[g][j], ws0 + (q * 4 + j) * NK, ctx) : 0.f;
            if (q < 2) {
                #pragma unroll
                for (int j = 0; j < 4; ++j)
                    t3[f * T3S + 16 + q * 4 + j] =
                        inimg ? rbf_eval<true>(acc1[g][j], ws0 + (16 + q * 4 + j) * NK, ctx) : 0.f;
            }
        }
    }
    __syncthreads();   // tbt fully consumed; reuse as reduction buffer

    // convT1 (24->1, pre-flipped f0t) + final; 4-way channel split across waves
    float* red = (float*)tbt;
    int gq = __builtin_amdgcn_readfirstlane(tid >> 6);
    int px = tid & 63, pr = px >> 3, pc = px & 7;
    float a = 0.f;
    #pragma unroll 1
    for (int cp = 0; cp < 3; ++cp) {
        int c = gq * 6 + cp * 2;               // even -> 8B-aligned float2
        const float* fb0 = f0t + c * 25;
        const float* fb1 = f0t + (c + 1) * 25;
        #pragma unroll
        for (int u = 0; u < 5; ++u)
            #pragma unroll
            for (int v = 0; v < 5; ++v) {
                float2 tp = *(const float2*)&t3[((pr + u) * 12 + (pc + v)) * T3S + c];
                a = fmaf(tp.x, fb0[u * 5 + v], a);
                a = fmaf(tp.y, fb1[u * 5 + v], a);
            }
    }
    red[tid] = a;
    __syncthreads();
    if (tid < 64) {
        float tot = red[tid] + red[64 + tid] + red[128 + tid] + red[192 + tid];
        int pix = (y0 + pr) * W + (x0 + pc);
        float elam = __expf(lamp[0]);
        float xv = x[pix], yv = y[pix];
        out[pix] = xv - (tot + elam * (xv - yv));
    }
}

extern "C" void kernel_launch(void* const* d_in, const int* in_sizes, int n_in,
                              void* d_out, int out_size, void* d_ws, size_t ws_size,
                              hipStream_t stream) {
    const float* x    = (const float*)d_in[0];
    const float* y    = (const float*)d_in[1];
    const float* f0   = (const float*)d_in[3];
    const float* f1   = (const float*)d_in[4];
    const float* aw0  = (const float*)d_in[5];
    const float* aw1  = (const float*)d_in[6];
    const float* mean = (const float*)d_in[7];
    const float* lamp = (const float*)d_in[8];
    float* out = (float*)d_out;

    float* w   = (float*)d_ws;
    float* f0n = w;                  // 600
    float* f0t = w + 640;            // 600
    v8s*  abuf = (v8s*)(w + 1536);   // 6400 * 16 B
    short* tb  = (short*)(w + 32768);

    k_prep<<<25, 256, 0, stream>>>(f0, f1, f0n, f0t, abuf);
    dim3 grid(W / 8, H / 8);         // 32 x 32 = 1024 blocks
    k_fuseA<<<grid, 256, 0, stream>>>(x, f0n, abuf, mean, aw0, aw1, tb);
    k_fuseB<<<grid, 256, 0, stream>>>(tb, abuf, f0t, mean, aw0, x, y, lamp, out);
}